// Round 1
// baseline (411.855 us; speedup 1.0000x reference)
//
#include <hip/hip_runtime.h>

#define N_SRC 50000
#define N_DST 50000
#define NEDGE 800000
#define IND   128
#define HEADS 4
#define CDIM  64
#define HC    256   // HEADS*CDIM

// ---------------------------------------------------------------------------
// zero scratch counters
__global__ void zero_kernel(int* __restrict__ p, int n) {
    int i = blockIdx.x * 256 + threadIdx.x;
    if (i < n) p[i] = 0;
}

// ---------------------------------------------------------------------------
// Fold W and att into [128][4]: WA[k][h] = sum_c W[k][h*64+c] * att[h][c]
__global__ void fold_kernel(const float* __restrict__ Wsrc, const float* __restrict__ Wdst,
                            const float* __restrict__ att_s, const float* __restrict__ att_d,
                            float* __restrict__ WsA, float* __restrict__ WdA) {
    int id = blockIdx.x * 256 + threadIdx.x;   // 0..1023
    const float* W = (id < 512) ? Wsrc : Wdst;
    const float* A = (id < 512) ? att_s : att_d;
    float* O       = (id < 512) ? WsA  : WdA;
    int q = id & 511;
    int k = q >> 2, h = q & 3;
    float acc = 0.f;
    for (int c = 0; c < CDIM; ++c)
        acc += W[k * HC + h * CDIM + c] * A[h * CDIM + c];
    O[q] = acc;   // q == k*4+h
}

// ---------------------------------------------------------------------------
// Per-node attention logits: a[n][h] = x[n,:] . WA[:,h].  One wave per node.
__global__ __launch_bounds__(256) void node_alpha_kernel(
        const float* __restrict__ x_src, const float* __restrict__ x_dst,
        const float* __restrict__ WsA, const float* __restrict__ WdA,
        float* __restrict__ a_s, float* __restrict__ a_d) {
    int gw   = (blockIdx.x * 256 + threadIdx.x) >> 6;
    int lane = threadIdx.x & 63;
    const float* xp; const float4* wa; float* op; int n;
    if (gw < N_SRC) { n = gw;         xp = x_src + (size_t)n * IND; wa = (const float4*)WsA; op = a_s; }
    else            { n = gw - N_SRC; xp = x_dst + (size_t)n * IND; wa = (const float4*)WdA; op = a_d; }
    float x0 = xp[lane], x1 = xp[lane + 64];
    float4 wa0 = wa[lane], wa1 = wa[lane + 64];
    float p0 = x0 * wa0.x + x1 * wa1.x;
    float p1 = x0 * wa0.y + x1 * wa1.y;
    float p2 = x0 * wa0.z + x1 * wa1.z;
    float p3 = x0 * wa0.w + x1 * wa1.w;
    for (int off = 32; off >= 1; off >>= 1) {
        p0 += __shfl_xor(p0, off, 64);
        p1 += __shfl_xor(p1, off, 64);
        p2 += __shfl_xor(p2, off, 64);
        p3 += __shfl_xor(p3, off, 64);
    }
    if (lane == 0) {
        op[n * 4 + 0] = p0; op[n * 4 + 1] = p1;
        op[n * 4 + 2] = p2; op[n * 4 + 3] = p3;
    }
}

// ---------------------------------------------------------------------------
// hs = x_src @ W_src stored TRANSPOSED per node: hsT[n][c][h]  (c*4+h fastest)
// Block: 256 thr, 16 rows. lane = channel c, wave rs handles rows rs*4..rs*4+3.
__global__ __launch_bounds__(256) void gemm_hsT_kernel(
        const float* __restrict__ x, const float* __restrict__ W,
        float* __restrict__ hsT) {
    __shared__ float xs[16][IND];   // 8 KB
    int tid = threadIdx.x;
    int c   = tid & 63;
    int rs  = tid >> 6;
    int rbase = blockIdx.x * 16;
    const float* xsrc = x + (size_t)rbase * IND;
    #pragma unroll
    for (int j = 0; j < 8; ++j) {
        int idx = tid + j * 256;
        ((float*)xs)[idx] = xsrc[idx];
    }
    __syncthreads();
    float4 acc0 = {0,0,0,0}, acc1 = acc0, acc2 = acc0, acc3 = acc0;
    #pragma unroll 8
    for (int k = 0; k < IND; ++k) {
        const float* wr = W + k * HC + c;
        float4 wv = { wr[0], wr[64], wr[128], wr[192] };   // heads 0..3 at channel c
        float xv0 = xs[rs * 4 + 0][k];
        float xv1 = xs[rs * 4 + 1][k];
        float xv2 = xs[rs * 4 + 2][k];
        float xv3 = xs[rs * 4 + 3][k];
        acc0.x += xv0 * wv.x; acc0.y += xv0 * wv.y; acc0.z += xv0 * wv.z; acc0.w += xv0 * wv.w;
        acc1.x += xv1 * wv.x; acc1.y += xv1 * wv.y; acc1.z += xv1 * wv.z; acc1.w += xv1 * wv.w;
        acc2.x += xv2 * wv.x; acc2.y += xv2 * wv.y; acc2.z += xv2 * wv.z; acc2.w += xv2 * wv.w;
        acc3.x += xv3 * wv.x; acc3.y += xv3 * wv.y; acc3.z += xv3 * wv.z; acc3.w += xv3 * wv.w;
    }
    float* o = hsT + (size_t)(rbase + rs * 4) * HC + c * 4;
    *(float4*)(o + 0 * HC) = acc0;
    *(float4*)(o + 1 * HC) = acc1;
    *(float4*)(o + 2 * HC) = acc2;
    *(float4*)(o + 3 * HC) = acc3;
}

// ---------------------------------------------------------------------------
// degree histogram over dst
__global__ void hist_kernel(const int* __restrict__ dst, int* __restrict__ deg) {
    int e = blockIdx.x * 256 + threadIdx.x;
    if (e < NEDGE) atomicAdd(&deg[dst[e]], 1);
}

// ---------------------------------------------------------------------------
// single-block exclusive scan of deg[0..n) -> row_ptr[0..n]
__global__ __launch_bounds__(1024) void scan_kernel(const int* __restrict__ deg,
                                                    int* __restrict__ row_ptr, int n) {
    __shared__ int wsum[16];
    __shared__ int woff[16];
    __shared__ int chunk_tot;
    int tid = threadIdx.x;
    int lane = tid & 63, wid = tid >> 6;
    int carry = 0;
    for (int base = 0; base < n; base += 4096) {
        int i0 = base + tid * 4;
        int v0 = (i0 + 0 < n) ? deg[i0 + 0] : 0;
        int v1 = (i0 + 1 < n) ? deg[i0 + 1] : 0;
        int v2 = (i0 + 2 < n) ? deg[i0 + 2] : 0;
        int v3 = (i0 + 3 < n) ? deg[i0 + 3] : 0;
        int t1 = v0, t2 = t1 + v1, t3 = t2 + v2, t4 = t3 + v3;
        int x = t4;
        for (int off = 1; off < 64; off <<= 1) {
            int u = __shfl_up(x, off, 64);
            if (lane >= off) x += u;
        }
        int wave_excl = x - t4;
        if (lane == 63) wsum[wid] = x;
        __syncthreads();
        if (wid == 0) {
            int orig = (lane < 16) ? wsum[lane] : 0;
            int y = orig;
            for (int off = 1; off < 16; off <<= 1) {
                int u = __shfl_up(y, off, 64);
                if (lane >= off) y += u;
            }
            if (lane < 16) woff[lane] = y - orig;
            if (lane == 15) chunk_tot = y;
        }
        __syncthreads();
        int tb = carry + woff[wid] + wave_excl;
        if (i0 + 0 < n) row_ptr[i0 + 0] = tb;
        if (i0 + 1 < n) row_ptr[i0 + 1] = tb + t1;
        if (i0 + 2 < n) row_ptr[i0 + 2] = tb + t2;
        if (i0 + 3 < n) row_ptr[i0 + 3] = tb + t3;
        carry += chunk_tot;
        __syncthreads();
    }
    if (tid == 0) row_ptr[n] = carry;
}

// ---------------------------------------------------------------------------
// CSR scatter + per-edge leaky-relu logits (4 heads) in CSR order
__global__ void scatter_kernel(const int* __restrict__ src, const int* __restrict__ dst,
                               const int* __restrict__ row_ptr, int* __restrict__ cnt,
                               int* __restrict__ col,
                               const float4* __restrict__ as4, const float4* __restrict__ ad4,
                               float4* __restrict__ lcsr) {
    int e = blockIdx.x * 256 + threadIdx.x;
    if (e >= NEDGE) return;
    int d = dst[e], s = src[e];
    int pos = row_ptr[d] + atomicAdd(&cnt[d], 1);
    col[pos] = s;
    float4 a = as4[s], b = ad4[d];
    float4 l;
    l.x = a.x + b.x; l.x = l.x > 0.f ? l.x : 0.2f * l.x;
    l.y = a.y + b.y; l.y = l.y > 0.f ? l.y : 0.2f * l.y;
    l.z = a.z + b.z; l.z = l.z > 0.f ? l.z : 0.2f * l.z;
    l.w = a.w + b.w; l.w = l.w > 0.f ? l.w : 0.2f * l.w;
    lcsr[pos] = l;
}

// ---------------------------------------------------------------------------
// One wave per dst node: online softmax over its edges, then weighted gather
// of hsT[src] (coalesced float4/lane = 1KB/wave per edge), mean heads + bias.
__device__ inline void onl_upd(float l, float& m, float& s) {
    if (l > m) { s = s * __expf(m - l) + 1.0f; m = l; }
    else       { s += __expf(l - m); }
}

__global__ __launch_bounds__(256) void aggregate_kernel(
        const int* __restrict__ row_ptr, const int* __restrict__ col,
        const float4* __restrict__ lcsr, const float* __restrict__ hsT,
        const float* __restrict__ bias, float* __restrict__ out) {
    int lane = threadIdx.x & 63;
    int i = (blockIdx.x * 256 + threadIdx.x) >> 6;
    if (i >= N_DST) return;
    int beg = row_ptr[i], end = row_ptr[i + 1];
    float bv = bias[lane];
    if (beg == end) { out[i * CDIM + lane] = bv; return; }

    // pass 1: per-head online max/sum across this node's edges
    float m0 = -1e30f, m1 = -1e30f, m2 = -1e30f, m3 = -1e30f;
    float s0 = 0.f, s1 = 0.f, s2 = 0.f, s3 = 0.f;
    for (int e = beg + lane; e < end; e += 64) {
        float4 l = lcsr[e];
        onl_upd(l.x, m0, s0); onl_upd(l.y, m1, s1);
        onl_upd(l.z, m2, s2); onl_upd(l.w, m3, s3);
    }
    #define MRG(m, s) { float m2_ = __shfl_xor(m, off, 64); float s2_ = __shfl_xor(s, off, 64); \
                        float nm_ = fmaxf(m, m2_); \
                        s = s * __expf(m - nm_) + s2_ * __expf(m2_ - nm_); m = nm_; }
    for (int off = 32; off >= 1; off >>= 1) {
        MRG(m0, s0) MRG(m1, s1) MRG(m2, s2) MRG(m3, s3)
    }
    #undef MRG
    float i0 = 1.f / (s0 + 1e-16f);
    float i1 = 1.f / (s1 + 1e-16f);
    float i2 = 1.f / (s2 + 1e-16f);
    float i3 = 1.f / (s3 + 1e-16f);

    // pass 2: weighted accumulate of hsT[src][c][h]
    float a0 = 0.f, a1 = 0.f, a2 = 0.f, a3 = 0.f;
    for (int cb = beg; cb < end; cb += 64) {
        int e = cb + lane;
        bool valid = e < end;
        int sn = valid ? col[e] : 0;
        float4 l;
        if (valid) l = lcsr[e];
        else       { l.x = -1e30f; l.y = -1e30f; l.z = -1e30f; l.w = -1e30f; }
        float w0 = __expf(l.x - m0) * i0;
        float w1 = __expf(l.y - m1) * i1;
        float w2 = __expf(l.z - m2) * i2;
        float w3 = __expf(l.w - m3) * i3;
        int cnt = end - cb; if (cnt > 64) cnt = 64;
        for (int j = 0; j < cnt; ++j) {
            int   snj = __shfl(sn, j, 64);
            float w0j = __shfl(w0, j, 64);
            float w1j = __shfl(w1, j, 64);
            float w2j = __shfl(w2, j, 64);
            float w3j = __shfl(w3, j, 64);
            const float4 h4 = *(const float4*)(hsT + (size_t)snj * HC + lane * 4);
            a0 += w0j * h4.x; a1 += w1j * h4.y;
            a2 += w2j * h4.z; a3 += w3j * h4.w;
        }
    }
    out[i * CDIM + lane] = 0.25f * (a0 + a1 + a2 + a3) + bv;
}

// ---------------------------------------------------------------------------
extern "C" void kernel_launch(void* const* d_in, const int* in_sizes, int n_in,
                              void* d_out, int out_size, void* d_ws, size_t ws_size,
                              hipStream_t stream) {
    const float* x_src   = (const float*)d_in[0];
    const float* x_dst   = (const float*)d_in[1];
    const int*   ei      = (const int*)d_in[2];   // [2][E]: src then dst
    const float* W_src   = (const float*)d_in[3];
    const float* W_dst   = (const float*)d_in[4];
    const float* att_src = (const float*)d_in[5];
    const float* att_dst = (const float*)d_in[6];
    const float* bias    = (const float*)d_in[7];
    float* out = (float*)d_out;

    char* ws = (char*)d_ws;
    float*  hsT     = (float*)ws;  ws += (size_t)N_SRC * HC * 4;       // 51.2 MB
    float4* lcsr    = (float4*)ws; ws += (size_t)NEDGE * 16;           // 12.8 MB
    int*    col     = (int*)ws;    ws += (size_t)NEDGE * 4;            // 3.2 MB
    float*  a_s     = (float*)ws;  ws += (size_t)N_SRC * 4 * 4;        // 0.8 MB
    float*  a_d     = (float*)ws;  ws += (size_t)N_DST * 4 * 4;        // 0.8 MB
    float*  WsA     = (float*)ws;  ws += 2048;
    float*  WdA     = (float*)ws;  ws += 2048;
    int*    row_ptr = (int*)ws;    ws += 50004 * 4;
    int*    deg     = (int*)ws;    ws += N_DST * 4;
    int*    cnt     = (int*)ws;    ws += N_DST * 4;                    // deg+cnt contiguous

    zero_kernel<<<(2 * N_DST + 255) / 256, 256, 0, stream>>>(deg, 2 * N_DST);
    fold_kernel<<<4, 256, 0, stream>>>(W_src, W_dst, att_src, att_dst, WsA, WdA);
    node_alpha_kernel<<<(2 * N_SRC) / 4, 256, 0, stream>>>(x_src, x_dst, WsA, WdA, a_s, a_d);
    gemm_hsT_kernel<<<N_SRC / 16, 256, 0, stream>>>(x_src, W_src, hsT);
    hist_kernel<<<NEDGE / 256, 256, 0, stream>>>(ei + NEDGE, deg);
    scan_kernel<<<1, 1024, 0, stream>>>(deg, row_ptr, N_DST);
    scatter_kernel<<<NEDGE / 256, 256, 0, stream>>>(ei, ei + NEDGE, row_ptr, cnt, col,
                                                    (const float4*)a_s, (const float4*)a_d, lcsr);
    aggregate_kernel<<<(N_DST + 3) / 4, 256, 0, stream>>>(row_ptr, col, lcsr, hsT, bias, out);
}

// Round 2
// 352.841 us; speedup vs baseline: 1.1673x; 1.1673x over previous
//
#include <hip/hip_runtime.h>
#include <hip/hip_bf16.h>

#define N_SRC 50000
#define N_DST 50000
#define NEDGE 800000
#define IND   128
#define HEADS 4
#define CDIM  64
#define HC    256   // HEADS*CDIM
#define NB_SCAN 49  // ceil(50000/1024)

// ---------------------------------------------------------------------------
__global__ void zero_kernel(int* __restrict__ p, int n) {
    int i = blockIdx.x * 256 + threadIdx.x;
    if (i < n) p[i] = 0;
}

// ---------------------------------------------------------------------------
// Fold W and att into [128][4]: WA[k][h] = sum_c W[k][h*64+c] * att[h][c]
__global__ void fold_kernel(const float* __restrict__ Wsrc, const float* __restrict__ Wdst,
                            const float* __restrict__ att_s, const float* __restrict__ att_d,
                            float* __restrict__ WsA, float* __restrict__ WdA) {
    int id = blockIdx.x * 256 + threadIdx.x;   // 0..1023
    const float* W = (id < 512) ? Wsrc : Wdst;
    const float* A = (id < 512) ? att_s : att_d;
    float* O       = (id < 512) ? WsA  : WdA;
    int q = id & 511;
    int k = q >> 2, h = q & 3;
    float acc = 0.f;
    for (int c = 0; c < CDIM; ++c)
        acc += W[k * HC + h * CDIM + c] * A[h * CDIM + c];
    O[q] = acc;   // q == k*4+h
}

// ---------------------------------------------------------------------------
// Per-node attention logits: a[n][h] = x[n,:] . WA[:,h].  One wave per node.
__global__ __launch_bounds__(256) void node_alpha_kernel(
        const float* __restrict__ x_src, const float* __restrict__ x_dst,
        const float* __restrict__ WsA, const float* __restrict__ WdA,
        float* __restrict__ a_s, float* __restrict__ a_d) {
    int gw   = (blockIdx.x * 256 + threadIdx.x) >> 6;
    int lane = threadIdx.x & 63;
    const float* xp; const float4* wa; float* op; int n;
    if (gw < N_SRC) { n = gw;         xp = x_src + (size_t)n * IND; wa = (const float4*)WsA; op = a_s; }
    else            { n = gw - N_SRC; xp = x_dst + (size_t)n * IND; wa = (const float4*)WdA; op = a_d; }
    float x0 = xp[lane], x1 = xp[lane + 64];
    float4 wa0 = wa[lane], wa1 = wa[lane + 64];
    float p0 = x0 * wa0.x + x1 * wa1.x;
    float p1 = x0 * wa0.y + x1 * wa1.y;
    float p2 = x0 * wa0.z + x1 * wa1.z;
    float p3 = x0 * wa0.w + x1 * wa1.w;
    for (int off = 32; off >= 1; off >>= 1) {
        p0 += __shfl_xor(p0, off, 64);
        p1 += __shfl_xor(p1, off, 64);
        p2 += __shfl_xor(p2, off, 64);
        p3 += __shfl_xor(p3, off, 64);
    }
    if (lane == 0) {
        op[n * 4 + 0] = p0; op[n * 4 + 1] = p1;
        op[n * 4 + 2] = p2; op[n * 4 + 3] = p3;
    }
}

// ---------------------------------------------------------------------------
// hs = x_src @ W_src, fp32 compute, stored bf16 TRANSPOSED per node:
// hsTb[n][ch*4+h].  Block: 256 thr = 4 waves, 64 rows/block.
// lane owns 4 CONSECUTIVE W cols -> one dwordx4 W load per k, wave covers the
// full 1KB W row.  x broadcast from LDS via b128 (k-unroll 4). 64 FMA/k/thread.
__global__ __launch_bounds__(256) void gemm_hsT_kernel(
        const float* __restrict__ x, const float* __restrict__ W,
        __hip_bfloat16* __restrict__ hsTb) {
    __shared__ float xs[64][IND];   // 32 KB
    int tid = threadIdx.x;
    int rbase = blockIdx.x * 64;
    // stage x (64 rows x 128) with bounds clamp for the last block
    {
        const float4* xsrc = (const float4*)x;
        float4* xl = (float4*)xs;
        int base4 = rbase * (IND / 4);
        const int lim4 = N_SRC * (IND / 4);
        #pragma unroll
        for (int j = 0; j < 8; ++j) {
            int idx = tid + j * 256;
            int g = base4 + idx;
            xl[idx] = (g < lim4) ? xsrc[g] : float4{0.f, 0.f, 0.f, 0.f};
        }
    }
    __syncthreads();
    int w = tid >> 6, c = tid & 63;
    int col0 = c << 2;         // 4 consecutive W cols
    int r0 = w << 4;           // 16 rows per wave
    float4 acc[16];
    #pragma unroll
    for (int r = 0; r < 16; ++r) acc[r] = float4{0.f, 0.f, 0.f, 0.f};

    #pragma unroll 1
    for (int k0 = 0; k0 < IND; k0 += 4) {
        float4 wv0 = *(const float4*)(W + (size_t)(k0 + 0) * HC + col0);
        float4 wv1 = *(const float4*)(W + (size_t)(k0 + 1) * HC + col0);
        float4 wv2 = *(const float4*)(W + (size_t)(k0 + 2) * HC + col0);
        float4 wv3 = *(const float4*)(W + (size_t)(k0 + 3) * HC + col0);
        #pragma unroll
        for (int r = 0; r < 16; ++r) {
            float4 xv = *(const float4*)&xs[r0 + r][k0];   // broadcast
            acc[r].x += xv.x * wv0.x + xv.y * wv1.x + xv.z * wv2.x + xv.w * wv3.x;
            acc[r].y += xv.x * wv0.y + xv.y * wv1.y + xv.z * wv2.y + xv.w * wv3.y;
            acc[r].z += xv.x * wv0.z + xv.y * wv1.z + xv.z * wv2.z + xv.w * wv3.z;
            acc[r].w += xv.x * wv0.w + xv.y * wv1.w + xv.z * wv2.w + xv.w * wv3.w;
        }
    }
    int h = col0 >> 6, ch = col0 & 63;
    #pragma unroll
    for (int r = 0; r < 16; ++r) {
        int n = rbase + r0 + r;
        if (n < N_SRC) {
            __hip_bfloat16* o = hsTb + (size_t)n * HC + (ch << 2) + h;
            o[0]  = __float2bfloat16(acc[r].x);
            o[4]  = __float2bfloat16(acc[r].y);
            o[8]  = __float2bfloat16(acc[r].z);
            o[12] = __float2bfloat16(acc[r].w);
        }
    }
}

// ---------------------------------------------------------------------------
__global__ void hist_kernel(const int* __restrict__ dst, int* __restrict__ deg) {
    int e = blockIdx.x * 256 + threadIdx.x;
    if (e < NEDGE) atomicAdd(&deg[dst[e]], 1);
}

// ---------------------------------------------------------------------------
// multi-block scan: (1) per-1024-chunk sums, (2) scan the 49 partials,
// (3) rescan chunk + add offset.
__global__ __launch_bounds__(256) void scan_part_kernel(const int* __restrict__ deg,
                                                        int* __restrict__ partial) {
    __shared__ int wsum[4];
    int tid = threadIdx.x, lane = tid & 63, wid = tid >> 6;
    int i0 = blockIdx.x * 1024 + tid * 4;
    int s = 0;
    #pragma unroll
    for (int j = 0; j < 4; ++j) if (i0 + j < N_DST) s += deg[i0 + j];
    for (int off = 32; off >= 1; off >>= 1) s += __shfl_xor(s, off, 64);
    if (lane == 0) wsum[wid] = s;
    __syncthreads();
    if (tid == 0) partial[blockIdx.x] = wsum[0] + wsum[1] + wsum[2] + wsum[3];
}

__global__ void scan_mid_kernel(const int* __restrict__ partial, int* __restrict__ offs,
                                int* __restrict__ row_ptr) {
    int l = threadIdx.x;   // 64 threads
    int v = (l < NB_SCAN) ? partial[l] : 0;
    int x = v;
    for (int off = 1; off < 64; off <<= 1) {
        int u = __shfl_up(x, off, 64);
        if (l >= off) x += u;
    }
    if (l < NB_SCAN) offs[l] = x - v;    // exclusive
    if (l == 0) row_ptr[N_DST] = NEDGE;
}

__global__ __launch_bounds__(256) void scan_write_kernel(const int* __restrict__ deg,
                                                         const int* __restrict__ offs,
                                                         int* __restrict__ row_ptr) {
    __shared__ int wsum[4];
    int tid = threadIdx.x, lane = tid & 63, wid = tid >> 6;
    int i0 = blockIdx.x * 1024 + tid * 4;
    int v0 = (i0 + 0 < N_DST) ? deg[i0 + 0] : 0;
    int v1 = (i0 + 1 < N_DST) ? deg[i0 + 1] : 0;
    int v2 = (i0 + 2 < N_DST) ? deg[i0 + 2] : 0;
    int v3 = (i0 + 3 < N_DST) ? deg[i0 + 3] : 0;
    int t1 = v0, t2 = t1 + v1, t3 = t2 + v2, t4 = t3 + v3;
    int x = t4;
    for (int off = 1; off < 64; off <<= 1) {
        int u = __shfl_up(x, off, 64);
        if (lane >= off) x += u;
    }
    int wave_excl = x - t4;
    if (lane == 63) wsum[wid] = x;
    __syncthreads();
    int woff = 0;
    for (int k = 0; k < wid; ++k) woff += wsum[k];
    int tb = offs[blockIdx.x] + woff + wave_excl;
    if (i0 + 0 < N_DST) row_ptr[i0 + 0] = tb;
    if (i0 + 1 < N_DST) row_ptr[i0 + 1] = tb + t1;
    if (i0 + 2 < N_DST) row_ptr[i0 + 2] = tb + t2;
    if (i0 + 3 < N_DST) row_ptr[i0 + 3] = tb + t3;
}

// ---------------------------------------------------------------------------
// CSR scatter + per-edge leaky-relu logits (4 heads)
__global__ void scatter_kernel(const int* __restrict__ src, const int* __restrict__ dst,
                               const int* __restrict__ row_ptr, int* __restrict__ cnt,
                               int* __restrict__ col,
                               const float4* __restrict__ as4, const float4* __restrict__ ad4,
                               float4* __restrict__ lcsr) {
    int e = blockIdx.x * 256 + threadIdx.x;
    if (e >= NEDGE) return;
    int d = dst[e], s = src[e];
    int pos = row_ptr[d] + atomicAdd(&cnt[d], 1);
    col[pos] = s;
    float4 a = as4[s], b = ad4[d];
    float4 l;
    l.x = a.x + b.x; l.x = l.x > 0.f ? l.x : 0.2f * l.x;
    l.y = a.y + b.y; l.y = l.y > 0.f ? l.y : 0.2f * l.y;
    l.z = a.z + b.z; l.z = l.z > 0.f ? l.z : 0.2f * l.z;
    l.w = a.w + b.w; l.w = l.w > 0.f ? l.w : 0.2f * l.w;
    lcsr[pos] = l;
}

// ---------------------------------------------------------------------------
// One wave per dst node. No max-subtraction (cancels in the softmax ratio;
// logits are O(10) so exp stays in fp32 range). Single pass: per-lane w=exp(l),
// per-lane partial denominator, serial-j gather of bf16 hsT rows (512B/edge),
// 2-way unrolled for two loads in flight.
__global__ __launch_bounds__(256) void aggregate_kernel(
        const int* __restrict__ row_ptr, const int* __restrict__ col,
        const float4* __restrict__ lcsr, const __hip_bfloat16* __restrict__ hsTb,
        const float* __restrict__ bias, float* __restrict__ out) {
    int lane = threadIdx.x & 63;
    int i = (blockIdx.x * 256 + threadIdx.x) >> 6;
    if (i >= N_DST) return;
    int beg = row_ptr[i], end = row_ptr[i + 1];
    float bv = bias[lane];
    if (beg == end) { out[i * CDIM + lane] = bv; return; }

    float s0 = 0.f, s1 = 0.f, s2 = 0.f, s3 = 0.f;
    float a0 = 0.f, a1 = 0.f, a2 = 0.f, a3 = 0.f;
    const int myoff = lane << 2;   // ushort offset within a node's 256-entry row

    for (int cb = beg; cb < end; cb += 64) {
        int e = cb + lane;
        bool valid = e < end;
        int sn = valid ? col[e] : 0;
        float4 l;
        if (valid) l = lcsr[e];
        else       { l.x = -1e30f; l.y = -1e30f; l.z = -1e30f; l.w = -1e30f; }
        float w0 = __expf(l.x), w1 = __expf(l.y), w2 = __expf(l.z), w3 = __expf(l.w);
        s0 += w0; s1 += w1; s2 += w2; s3 += w3;

        int cnt = end - cb; if (cnt > 64) cnt = 64;
        int j = 0;
        for (; j + 2 <= cnt; j += 2) {
            int sA = __shfl(sn, j, 64);
            int sB = __shfl(sn, j + 1, 64);
            uint2 hA = *(const uint2*)((const unsigned short*)hsTb + (size_t)sA * HC + myoff);
            uint2 hB = *(const uint2*)((const unsigned short*)hsTb + (size_t)sB * HC + myoff);
            float wA0 = __shfl(w0, j, 64), wA1 = __shfl(w1, j, 64);
            float wA2 = __shfl(w2, j, 64), wA3 = __shfl(w3, j, 64);
            float wB0 = __shfl(w0, j + 1, 64), wB1 = __shfl(w1, j + 1, 64);
            float wB2 = __shfl(w2, j + 1, 64), wB3 = __shfl(w3, j + 1, 64);
            float fA0 = __uint_as_float(hA.x << 16);
            float fA1 = __uint_as_float(hA.x & 0xffff0000u);
            float fA2 = __uint_as_float(hA.y << 16);
            float fA3 = __uint_as_float(hA.y & 0xffff0000u);
            a0 += wA0 * fA0; a1 += wA1 * fA1; a2 += wA2 * fA2; a3 += wA3 * fA3;
            float fB0 = __uint_as_float(hB.x << 16);
            float fB1 = __uint_as_float(hB.x & 0xffff0000u);
            float fB2 = __uint_as_float(hB.y << 16);
            float fB3 = __uint_as_float(hB.y & 0xffff0000u);
            a0 += wB0 * fB0; a1 += wB1 * fB1; a2 += wB2 * fB2; a3 += wB3 * fB3;
        }
        if (j < cnt) {
            int sA = __shfl(sn, j, 64);
            uint2 hA = *(const uint2*)((const unsigned short*)hsTb + (size_t)sA * HC + myoff);
            float wA0 = __shfl(w0, j, 64), wA1 = __shfl(w1, j, 64);
            float wA2 = __shfl(w2, j, 64), wA3 = __shfl(w3, j, 64);
            float fA0 = __uint_as_float(hA.x << 16);
            float fA1 = __uint_as_float(hA.x & 0xffff0000u);
            float fA2 = __uint_as_float(hA.y << 16);
            float fA3 = __uint_as_float(hA.y & 0xffff0000u);
            a0 += wA0 * fA0; a1 += wA1 * fA1; a2 += wA2 * fA2; a3 += wA3 * fA3;
        }
    }
    for (int off = 32; off >= 1; off >>= 1) {
        s0 += __shfl_xor(s0, off, 64);
        s1 += __shfl_xor(s1, off, 64);
        s2 += __shfl_xor(s2, off, 64);
        s3 += __shfl_xor(s3, off, 64);
    }
    out[i * CDIM + lane] = 0.25f * (a0 / (s0 + 1e-16f) + a1 / (s1 + 1e-16f)
                                  + a2 / (s2 + 1e-16f) + a3 / (s3 + 1e-16f)) + bv;
}

// ---------------------------------------------------------------------------
extern "C" void kernel_launch(void* const* d_in, const int* in_sizes, int n_in,
                              void* d_out, int out_size, void* d_ws, size_t ws_size,
                              hipStream_t stream) {
    const float* x_src   = (const float*)d_in[0];
    const float* x_dst   = (const float*)d_in[1];
    const int*   ei      = (const int*)d_in[2];   // [2][E]: src then dst
    const float* W_src   = (const float*)d_in[3];
    const float* W_dst   = (const float*)d_in[4];
    const float* att_src = (const float*)d_in[5];
    const float* att_dst = (const float*)d_in[6];
    const float* bias    = (const float*)d_in[7];
    float* out = (float*)d_out;

    char* ws = (char*)d_ws;
    __hip_bfloat16* hsTb = (__hip_bfloat16*)ws; ws += (size_t)N_SRC * HC * 2;  // 25.6 MB
    float4* lcsr    = (float4*)ws; ws += (size_t)NEDGE * 16;           // 12.8 MB
    int*    col     = (int*)ws;    ws += (size_t)NEDGE * 4;            // 3.2 MB
    float*  a_s     = (float*)ws;  ws += (size_t)N_SRC * 4 * 4;
    float*  a_d     = (float*)ws;  ws += (size_t)N_DST * 4 * 4;
    float*  WsA     = (float*)ws;  ws += 2048;
    float*  WdA     = (float*)ws;  ws += 2048;
    int*    row_ptr = (int*)ws;    ws += 50004 * 4;
    int*    deg     = (int*)ws;    ws += N_DST * 4;
    int*    cnt     = (int*)ws;    ws += N_DST * 4;                    // deg+cnt contiguous
    int*    partial = (int*)ws;    ws += 64 * 4;
    int*    offs    = (int*)ws;    ws += 64 * 4;

    zero_kernel<<<(2 * N_DST + 255) / 256, 256, 0, stream>>>(deg, 2 * N_DST);
    fold_kernel<<<4, 256, 0, stream>>>(W_src, W_dst, att_src, att_dst, WsA, WdA);
    node_alpha_kernel<<<(2 * N_SRC) / 4, 256, 0, stream>>>(x_src, x_dst, WsA, WdA, a_s, a_d);
    gemm_hsT_kernel<<<(N_SRC + 63) / 64, 256, 0, stream>>>(x_src, W_src, hsTb);
    hist_kernel<<<NEDGE / 256, 256, 0, stream>>>(ei + NEDGE, deg);
    scan_part_kernel<<<NB_SCAN, 256, 0, stream>>>(deg, partial);
    scan_mid_kernel<<<1, 64, 0, stream>>>(partial, offs, row_ptr);
    scan_write_kernel<<<NB_SCAN, 256, 0, stream>>>(deg, offs, row_ptr);
    scatter_kernel<<<NEDGE / 256, 256, 0, stream>>>(ei, ei + NEDGE, row_ptr, cnt, col,
                                                    (const float4*)a_s, (const float4*)a_d, lcsr);
    aggregate_kernel<<<(N_DST + 3) / 4, 256, 0, stream>>>(row_ptr, col, lcsr, hsTb, bias, out);
}